// Round 6
// baseline (698.752 us; speedup 1.0000x reference)
//
#include <hip/hip_runtime.h>
#include <hip/hip_bf16.h>
#include <math.h>

typedef __hip_bfloat16 bf16;
typedef __attribute__((ext_vector_type(8))) short bf16x8;   // 8 bf16 = 4 VGPR
typedef __attribute__((ext_vector_type(4))) float f32x4;

__device__ __forceinline__ float b2f(bf16 v) { return __bfloat162float(v); }
__device__ __forceinline__ bf16  f2b(float v) { return __float2bfloat16(v); }

constexpr int Bc = 2, Tc = 1024, Dc = 2048, Hc = 16, HKVc = 4, DHc = 128, Fc = 5632;
constexpr int Mr = Bc * Tc;                      // 2048 rows
constexpr int Nqkv = Hc * DHc + 2 * HKVc * DHc;  // 3072

// async 16B global->LDS (lands at wave-uniform base + lane*16)
__device__ __forceinline__ void g2l16(void* lds, const void* g) {
  __builtin_amdgcn_global_load_lds(
      (const __attribute__((address_space(1))) unsigned int*)g,
      (__attribute__((address_space(3))) unsigned int*)lds, 16, 0, 0);
}

// ------------------------------------------------------- transpose + cast ---
// src fp32 [K][N] -> dst bf16 [rowmul*n0+nl][K]. rowmul=1: plain B^T.
// rowmul=2 (+dst pre-offset half*64*K): interleaved W13 layout.
__global__ __launch_bounds__(256) void tcast_k(const float* __restrict__ src,
                                               bf16* __restrict__ dst,
                                               int N, int K, int rowmul) {
  __shared__ bf16 tile[64][68];
  const int t = threadIdx.x;
  const int n0 = blockIdx.x * 64, k0 = blockIdx.y * 64;
#pragma unroll
  for (int it = 0; it < 4; ++it) {
    const int kl = it * 16 + (t >> 4);
    const int nl = (t & 15) * 4;
    float4 v = *reinterpret_cast<const float4*>(src + (size_t)(k0 + kl) * N + n0 + nl);
    tile[kl][nl]     = f2b(v.x);
    tile[kl][nl + 1] = f2b(v.y);
    tile[kl][nl + 2] = f2b(v.z);
    tile[kl][nl + 3] = f2b(v.w);
  }
  __syncthreads();
  union { uint4 u; bf16 h[8]; } o;   // 16 B
#pragma unroll
  for (int it = 0; it < 2; ++it) {
    const int nl = it * 32 + (t >> 3);
    const int kl = (t & 7) * 8;
#pragma unroll
    for (int j = 0; j < 8; ++j) o.h[j] = tile[kl + j][nl];
    *reinterpret_cast<uint4*>(dst + (size_t)(rowmul * n0 + nl) * K + k0 + kl) = o.u;
  }
}

// ---------------------------------------------------------------- RMSNorm ---
__global__ __launch_bounds__(256) void rmsnorm_k(const float* __restrict__ x,
                                                 const float* __restrict__ w,
                                                 bf16* __restrict__ out) {
  const size_t rbase = (size_t)blockIdx.x * Dc;
  float ss = 0.f;
  for (int i = threadIdx.x; i < Dc; i += 256) {
    float v = x[rbase + i];
    ss += v * v;
  }
#pragma unroll
  for (int off = 32; off > 0; off >>= 1) ss += __shfl_down(ss, off, 64);
  __shared__ float red[4];
  const int lane = threadIdx.x & 63, wid = threadIdx.x >> 6;
  if (lane == 0) red[wid] = ss;
  __syncthreads();
  const float scale = rsqrtf((red[0] + red[1] + red[2] + red[3]) / (float)Dc + 1e-6f);
  for (int i = threadIdx.x; i < Dc; i += 256)
    out[rbase + i] = f2b(x[rbase + i] * scale * w[i]);
}

// ----------------------------------------------------- MFMA GEMM (m97-ish) --
template <bool ADDRES>
__global__ __launch_bounds__(256) void gemm128(const bf16* __restrict__ A,
                                               const bf16* __restrict__ Bt,
                                               const float* __restrict__ Res,
                                               void* __restrict__ Out,
                                               int N, int K) {
  __shared__ __align__(16) bf16 As[128 * 32];
  __shared__ __align__(16) bf16 Bs[128 * 32];
  const int t = threadIdx.x;
  const int bm = blockIdx.y * 128, bn = blockIdx.x * 128;
  const int lane = t & 63, wv = t >> 6;
  const int wm = (wv & 1) * 64, wn = (wv >> 1) * 64;
  const int sr = t >> 2, sc = (t & 3) * 8;
  const bf16* ga = A + (size_t)(bm + sr) * K + sc;
  const bf16* gb = Bt + (size_t)(bn + sr) * K + sc;
  bf16* lA0 = As + sr * 32 + sc;
  bf16* lA1 = As + (64 + sr) * 32 + sc;
  bf16* lB0 = Bs + sr * 32 + sc;
  bf16* lB1 = Bs + (64 + sr) * 32 + sc;
  const size_t rstep = (size_t)64 * K;
  f32x4 acc[4][4] = {};
  const int fr = lane & 15, fko = (lane >> 4) * 8;
  for (int k0 = 0; k0 < K; k0 += 32) {
    __syncthreads();
    g2l16(lA0, ga + k0);
    g2l16(lA1, ga + rstep + k0);
    g2l16(lB0, gb + k0);
    g2l16(lB1, gb + rstep + k0);
    __syncthreads();
    bf16x8 af[4], bff[4];
#pragma unroll
    for (int i = 0; i < 4; ++i)
      af[i] = *reinterpret_cast<const bf16x8*>(As + (wm + i * 16 + fr) * 32 + fko);
#pragma unroll
    for (int j = 0; j < 4; ++j)
      bff[j] = *reinterpret_cast<const bf16x8*>(Bs + (wn + j * 16 + fr) * 32 + fko);
#pragma unroll
    for (int i = 0; i < 4; ++i)
#pragma unroll
      for (int j = 0; j < 4; ++j)
        acc[i][j] = __builtin_amdgcn_mfma_f32_16x16x32_bf16(af[i], bff[j], acc[i][j], 0, 0, 0);
  }
  const int er = (lane >> 4) * 4, ec = lane & 15;
#pragma unroll
  for (int i = 0; i < 4; ++i)
#pragma unroll
    for (int j = 0; j < 4; ++j) {
      const int row = bm + wm + i * 16 + er;
      const int col = bn + wn + j * 16 + ec;
#pragma unroll
      for (int r = 0; r < 4; ++r) {
        const size_t idx = (size_t)(row + r) * N + col;
        if (ADDRES) ((float*)Out)[idx] = Res[idx] + acc[i][j][r];
        else        ((bf16*)Out)[idx] = f2b(acc[i][j][r]);
      }
    }
}

// ------------------------------------------- fused FFN 128-tile MFMA GEMM ---
// W13t [2F][K]: block bn = one 64-col group; rows bn..bn+63 = W1 cols,
// bn+64..bn+127 = W3 cols. Epilogue: up-waves post u via LDS, gate-waves
// compute silu(g)*u -> act[M][F].
__global__ __launch_bounds__(256) void ffn128(const bf16* __restrict__ A,
                                              const bf16* __restrict__ W13t,
                                              bf16* __restrict__ act, int K) {
  __shared__ __align__(16) bf16 As[128 * 32];
  __shared__ __align__(16) bf16 Bs[128 * 32];
  __shared__ __align__(16) bf16 Xs[128 * 68];
  const int t = threadIdx.x;
  const int bm = blockIdx.y * 128, bn = blockIdx.x * 128;
  const int lane = t & 63, wv = t >> 6;
  const int wm = (wv & 1) * 64, wn = (wv >> 1) * 64;
  const int sr = t >> 2, sc = (t & 3) * 8;
  const bf16* ga = A + (size_t)(bm + sr) * K + sc;
  const bf16* gb = W13t + (size_t)(bn + sr) * K + sc;
  bf16* lA0 = As + sr * 32 + sc;
  bf16* lA1 = As + (64 + sr) * 32 + sc;
  bf16* lB0 = Bs + sr * 32 + sc;
  bf16* lB1 = Bs + (64 + sr) * 32 + sc;
  const size_t rstep = (size_t)64 * K;
  f32x4 acc[4][4] = {};
  const int fr = lane & 15, fko = (lane >> 4) * 8;
  for (int k0 = 0; k0 < K; k0 += 32) {
    __syncthreads();
    g2l16(lA0, ga + k0);
    g2l16(lA1, ga + rstep + k0);
    g2l16(lB0, gb + k0);
    g2l16(lB1, gb + rstep + k0);
    __syncthreads();
    bf16x8 af[4], bff[4];
#pragma unroll
    for (int i = 0; i < 4; ++i)
      af[i] = *reinterpret_cast<const bf16x8*>(As + (wm + i * 16 + fr) * 32 + fko);
#pragma unroll
    for (int j = 0; j < 4; ++j)
      bff[j] = *reinterpret_cast<const bf16x8*>(Bs + (wn + j * 16 + fr) * 32 + fko);
#pragma unroll
    for (int i = 0; i < 4; ++i)
#pragma unroll
      for (int j = 0; j < 4; ++j)
        acc[i][j] = __builtin_amdgcn_mfma_f32_16x16x32_bf16(af[i], bff[j], acc[i][j], 0, 0, 0);
  }
  const int er = (lane >> 4) * 4, ec = lane & 15;
  if (wv >= 2) {  // up waves (wn=64): post u to LDS as bf16
#pragma unroll
    for (int i = 0; i < 4; ++i)
#pragma unroll
      for (int j = 0; j < 4; ++j)
#pragma unroll
        for (int r = 0; r < 4; ++r)
          Xs[(wm + i * 16 + er + r) * 68 + j * 16 + ec] = f2b(acc[i][j][r]);
  }
  __syncthreads();
  if (wv < 2) {  // gate waves (wn=0): silu(g)*u
    const int colbase = (bn >> 1);  // = group*64
#pragma unroll
    for (int i = 0; i < 4; ++i)
#pragma unroll
      for (int j = 0; j < 4; ++j)
#pragma unroll
        for (int r = 0; r < 4; ++r) {
          const int rl = wm + i * 16 + er + r;
          const int c = j * 16 + ec;
          const float g = acc[i][j][r];
          const float u = b2f(Xs[rl * 68 + c]);
          const float sg = g / (1.f + __expf(-g));
          act[(size_t)(bm + rl) * Fc + colbase + c] = f2b(sg * u);
        }
  }
}

// ---------------------------------------------- repack: RoPE + Q/K/V split --
// qkv packed [M][3072] -> Qr (pre-scaled by 1/sqrt(DH)), Kr, Vt[B,HKV,DH,T]
__global__ __launch_bounds__(256) void repack_k(const bf16* __restrict__ qkv,
                                                const float* __restrict__ cosb,
                                                const float* __restrict__ sinb,
                                                bf16* __restrict__ Qr,
                                                bf16* __restrict__ Kr,
                                                bf16* __restrict__ Vt) {
  const float SCL = 0.08838834764831845f;
  const int bt = blockIdx.x;
  const int b = bt >> 10, tp = bt & (Tc - 1);
  const int t0 = threadIdx.x;
  const bf16* row = qkv + (size_t)bt * Nqkv;
#pragma unroll
  for (int k = 0; k < 4; ++k) {      // Q: 1024 rope pairs (+scale)
    int p2 = k * 256 + t0;
    int hh = p2 >> 6, i = p2 & 63;
    float c = cosb[tp * 64 + i], sn = sinb[tp * 64 + i];
    float x0 = b2f(row[hh * 128 + 2 * i]), x1 = b2f(row[hh * 128 + 2 * i + 1]);
    bf16* dst = Qr + ((size_t)(b * Hc + hh) * Tc + tp) * DHc + 2 * i;
    dst[0] = f2b((x0 * c - x1 * sn) * SCL);
    dst[1] = f2b((x0 * sn + x1 * c) * SCL);
  }
  {                                   // K: 256 rope pairs
    int hh = t0 >> 6, i = t0 & 63;
    float c = cosb[tp * 64 + i], sn = sinb[tp * 64 + i];
    float x0 = b2f(row[2048 + hh * 128 + 2 * i]), x1 = b2f(row[2048 + hh * 128 + 2 * i + 1]);
    bf16* dst = Kr + ((size_t)(b * HKVc + hh) * Tc + tp) * DHc + 2 * i;
    dst[0] = f2b(x0 * c - x1 * sn);
    dst[1] = f2b(x0 * sn + x1 * c);
  }
#pragma unroll
  for (int k = 0; k < 2; ++k) {      // V: 512 elems, transposed store
    int e = k * 256 + t0;
    int kvh = e >> 7, dd = e & 127;
    Vt[((size_t)(b * HKVc + kvh) * DHc + dd) * Tc + tp] = row[2560 + e];
  }
}

// ----------------------------------------------------- MFMA flash attention --
// block = (b, h, 64-row q-tile); 4 waves x 16 q-rows; 64-key tiles;
// register-prefetch of next K/V tile hides global latency behind compute.
__global__ __launch_bounds__(256) void fattn(const bf16* __restrict__ Qr,
                                             const bf16* __restrict__ Kr,
                                             const bf16* __restrict__ Vt,
                                             bf16* __restrict__ ao) {
  __shared__ __align__(16) bf16 Ks[64 * 136];    // [key][d], +8 pad
  __shared__ __align__(16) bf16 Vts[128 * 72];   // [d][key], +8 pad
  __shared__ __align__(16) bf16 Ps[4][16 * 72];  // per-wave P
  const int idx = blockIdx.x;
  const int r = idx & 15;
  const int qt = (r & 1) ? (15 - (r >> 1)) : (r >> 1);  // pair-balanced
  const int h = (idx >> 4) & 15;
  const int b = idx >> 8;
  const int kv = h >> 2;
  const int t = threadIdx.x, lane = t & 63, wv = t >> 6;
  const int fr = lane & 15, quad = lane >> 4;

  const bf16* Qbase = Qr + ((size_t)(b * Hc + h) * Tc + qt * 64) * DHc;
  const bf16* Kbase = Kr + (size_t)(b * HKVc + kv) * Tc * DHc;
  const bf16* Vbase = Vt + (size_t)(b * HKVc + kv) * DHc * Tc;

  bf16x8 qf[4];
#pragma unroll
  for (int c = 0; c < 4; ++c)
    qf[c] = *reinterpret_cast<const bf16x8*>(Qbase + (size_t)(wv * 16 + fr) * DHc + c * 32 + quad * 8);

  // precomputed staging source offsets / LDS targets
  int kRow[4], kC[4], vRow[4], vC[4];
#pragma unroll
  for (int i2 = 0; i2 < 4; ++i2) {
    int f1 = i2 * 256 + t;
    kRow[i2] = f1 >> 4; kC[i2] = (f1 & 15) * 8;
    vRow[i2] = f1 >> 3; vC[i2] = (f1 & 7) * 8;
  }

  uint4 pk[4], pv[4];
#pragma unroll
  for (int i2 = 0; i2 < 4; ++i2) {
    pk[i2] = *reinterpret_cast<const uint4*>(Kbase + (size_t)kRow[i2] * DHc + kC[i2]);
    pv[i2] = *reinterpret_cast<const uint4*>(Vbase + (size_t)vRow[i2] * Tc + vC[i2]);
  }

  float m[4], l[4];
  f32x4 o[8] = {};
#pragma unroll
  for (int r2 = 0; r2 < 4; ++r2) { m[r2] = -3.0e38f; l[r2] = 0.f; }

  for (int kt = 0; kt <= qt; ++kt) {
    __syncthreads();   // prev iter's Ks/Vts reads complete
#pragma unroll
    for (int i2 = 0; i2 < 4; ++i2) {
      *reinterpret_cast<uint4*>(&Ks[kRow[i2] * 136 + kC[i2]]) = pk[i2];
      *reinterpret_cast<uint4*>(&Vts[vRow[i2] * 72 + vC[i2]]) = pv[i2];
    }
    __syncthreads();
    if (kt < qt) {  // prefetch next tile; latency hidden behind compute below
      const bf16* kn = Kbase + (size_t)(kt + 1) * 64 * DHc;
      const bf16* vn = Vbase + (size_t)(kt + 1) * 64;
#pragma unroll
      for (int i2 = 0; i2 < 4; ++i2) {
        pk[i2] = *reinterpret_cast<const uint4*>(kn + (size_t)kRow[i2] * DHc + kC[i2]);
        pv[i2] = *reinterpret_cast<const uint4*>(vn + (size_t)vRow[i2] * Tc + vC[i2]);
      }
    }
    // S = Q K^T  (16 MFMA)  [Q pre-scaled]
    f32x4 s[4];
#pragma unroll
    for (int cb = 0; cb < 4; ++cb) {
      f32x4 acc = {};
#pragma unroll
      for (int kc = 0; kc < 4; ++kc) {
        bf16x8 kf = *reinterpret_cast<const bf16x8*>(&Ks[(cb * 16 + fr) * 136 + kc * 32 + quad * 8]);
        acc = __builtin_amdgcn_mfma_f32_16x16x32_bf16(qf[kc], kf, acc, 0, 0, 0);
      }
      s[cb] = acc;
    }
    if (kt == qt) {  // causal mask, diagonal tile only
#pragma unroll
      for (int cb = 0; cb < 4; ++cb)
#pragma unroll
        for (int r2 = 0; r2 < 4; ++r2) {
          int key = cb * 16 + fr;
          int qg = wv * 16 + quad * 4 + r2;
          if (key > qg) s[cb][r2] = -3.0e38f;
        }
    }
    // online softmax
    float tm[4], ts[4];
#pragma unroll
    for (int r2 = 0; r2 < 4; ++r2)
      tm[r2] = fmaxf(fmaxf(s[0][r2], s[1][r2]), fmaxf(s[2][r2], s[3][r2]));
#pragma unroll
    for (int off = 1; off < 16; off <<= 1)
#pragma unroll
      for (int r2 = 0; r2 < 4; ++r2)
        tm[r2] = fmaxf(tm[r2], __shfl_xor(tm[r2], off, 64));
    float al[4];
#pragma unroll
    for (int r2 = 0; r2 < 4; ++r2) {
      float mn = fmaxf(m[r2], tm[r2]);
      al[r2] = __expf(m[r2] - mn);
      m[r2] = mn;
      ts[r2] = 0.f;
    }
#pragma unroll
    for (int cb = 0; cb < 4; ++cb)
#pragma unroll
      for (int r2 = 0; r2 < 4; ++r2) {
        float e = __expf(s[cb][r2] - m[r2]);
        s[cb][r2] = e;
        ts[r2] += e;
      }
#pragma unroll
    for (int off = 1; off < 16; off <<= 1)
#pragma unroll
      for (int r2 = 0; r2 < 4; ++r2)
        ts[r2] += __shfl_xor(ts[r2], off, 64);
#pragma unroll
    for (int r2 = 0; r2 < 4; ++r2) l[r2] = l[r2] * al[r2] + ts[r2];
#pragma unroll
    for (int db = 0; db < 8; ++db)
#pragma unroll
      for (int r2 = 0; r2 < 4; ++r2) o[db][r2] *= al[r2];
    // P: C-layout regs -> LDS -> A-layout frags (per-wave buffer)
    bf16* pw = Ps[wv];
#pragma unroll
    for (int cb = 0; cb < 4; ++cb)
#pragma unroll
      for (int r2 = 0; r2 < 4; ++r2)
        pw[(quad * 4 + r2) * 72 + cb * 16 + fr] = f2b(s[cb][r2]);
    bf16x8 pa[2];
    pa[0] = *reinterpret_cast<const bf16x8*>(&pw[fr * 72 + quad * 8]);
    pa[1] = *reinterpret_cast<const bf16x8*>(&pw[fr * 72 + 32 + quad * 8]);
    // O += P V  (16 MFMA)
#pragma unroll
    for (int db = 0; db < 8; ++db) {
      bf16x8 v0 = *reinterpret_cast<const bf16x8*>(&Vts[(db * 16 + fr) * 72 + quad * 8]);
      bf16x8 v1 = *reinterpret_cast<const bf16x8*>(&Vts[(db * 16 + fr) * 72 + 32 + quad * 8]);
      o[db] = __builtin_amdgcn_mfma_f32_16x16x32_bf16(pa[0], v0, o[db], 0, 0, 0);
      o[db] = __builtin_amdgcn_mfma_f32_16x16x32_bf16(pa[1], v1, o[db], 0, 0, 0);
    }
  }
#pragma unroll
  for (int r2 = 0; r2 < 4; ++r2) {
    float inv = 1.f / l[r2];
    int qg = qt * 64 + wv * 16 + quad * 4 + r2;
    bf16* orow = ao + (size_t)(b * Tc + qg) * Dc + h * DHc;
#pragma unroll
    for (int db = 0; db < 8; ++db)
      orow[db * 16 + fr] = f2b(o[db][r2] * inv);
  }
}

// ------------------------------------------------------------------ launch --
extern "C" void kernel_launch(void* const* d_in, const int* in_sizes, int n_in,
                              void* d_out, int out_size, void* d_ws, size_t ws_size,
                              hipStream_t stream) {
  const float* x    = (const float*)d_in[0];
  const float* fcos = (const float*)d_in[1];
  const float* fsin = (const float*)d_in[2];
  const float* wn1  = (const float*)d_in[3];
  const float* wn2  = (const float*)d_in[4];
  const float* wq   = (const float*)d_in[5];
  const float* wk   = (const float*)d_in[6];
  const float* wv   = (const float*)d_in[7];
  const float* wo   = (const float*)d_in[8];
  const float* w1   = (const float*)d_in[9];
  const float* w2   = (const float*)d_in[10];
  const float* w3   = (const float*)d_in[11];

  char* p = (char*)d_ws;
  bf16* wqkv_t = (bf16*)p;                 p += (size_t)Nqkv * Dc * 2;   // 12.58 MB
  bf16* qkv    = (bf16*)p;                 p += (size_t)Mr * Nqkv * 2;   // 12.58 MB
  float* xat   = (float*)d_ws;             // aliases wqkv_t+qkv (dead by wo-gemm)
  bf16* wo_t  = (bf16*)p;                  p += (size_t)Dc * Dc * 2;     // 8.39 MB
  bf16* W13t  = (bf16*)p;                  p += (size_t)2 * Fc * Dc * 2; // 46.14 MB
  bf16* w2t   = W13t;                      // aliases W13t (dead after ffn128)
  bf16* xn    = (bf16*)p;                  p += (size_t)Mr * Dc * 2;     // 8.39 MB (reused as h)
  bf16* ao    = (bf16*)p;                  p += (size_t)Mr * Dc * 2;     // 8.39 MB
  bf16* act   = (bf16*)p;                  p += (size_t)Mr * Fc * 2;     // 23.07 MB
  bf16* hb = xn;
  // Qr/Kr/Vt alias the act region (act written only after attention is done)
  bf16* Qr  = act;                                       // 8.39 MB
  bf16* Kr  = act + (size_t)Mr * Hc * DHc;               // 2.10 MB
  bf16* Vtb = Kr + (size_t)Mr * HKVc * DHc;              // 2.10 MB

  const dim3 blk(256);
  tcast_k<<<dim3(32, 32), blk, 0, stream>>>(wq, wqkv_t, 2048, 2048, 1);
  tcast_k<<<dim3(8, 32), blk, 0, stream>>>(wk, wqkv_t + (size_t)2048 * 2048, 512, 2048, 1);
  tcast_k<<<dim3(8, 32), blk, 0, stream>>>(wv, wqkv_t + (size_t)2560 * 2048, 512, 2048, 1);
  tcast_k<<<dim3(32, 32), blk, 0, stream>>>(wo, wo_t, 2048, 2048, 1);
  tcast_k<<<dim3(88, 32), blk, 0, stream>>>(w1, W13t, 5632, 2048, 2);                       // half 0
  tcast_k<<<dim3(88, 32), blk, 0, stream>>>(w3, W13t + (size_t)64 * 2048, 5632, 2048, 2);   // half 1

  rmsnorm_k<<<Mr, blk, 0, stream>>>(x, wn1, xn);
  gemm128<false><<<dim3(Nqkv / 128, Mr / 128), blk, 0, stream>>>(xn, wqkv_t, nullptr, qkv, Nqkv, Dc);
  repack_k<<<Mr, blk, 0, stream>>>(qkv, fcos, fsin, Qr, Kr, Vtb);
  fattn<<<Bc * Hc * 16, blk, 0, stream>>>(Qr, Kr, Vtb, ao);
  gemm128<true><<<dim3(Dc / 128, Mr / 128), blk, 0, stream>>>(ao, wo_t, x, xat, Dc, Dc);
  rmsnorm_k<<<Mr, blk, 0, stream>>>(xat, wn2, hb);
  ffn128<<<dim3(2 * Fc / 128, Mr / 128), blk, 0, stream>>>(hb, W13t, act, Dc);
  tcast_k<<<dim3(32, 88), blk, 0, stream>>>(w2, w2t, 2048, 5632, 1);
  gemm128<true><<<dim3(Dc / 128, Mr / 128), blk, 0, stream>>>(act, w2t, xat, (float*)d_out, Dc, Fc);
}